// Round 6
// baseline (377.579 us; speedup 1.0000x reference)
//
#include <hip/hip_runtime.h>
#include <math.h>

#define DD    64
#define TT    256
#define NROW  4096
#define RV    8            // valid rows per block (tile rows 8..15 are benign zeros)
#define BLK   512
#define GRID  (NROW / RV)  // 512 blocks -> 2 blocks/CU -> 4 waves/SIMD (2 indep chains)

typedef __attribute__((ext_vector_type(8))) short  short8;
typedef __attribute__((ext_vector_type(4))) float  f32x4;

// Raw workgroup barrier: LDS visibility only (lgkmcnt), no vmcnt drain.
// Global loads/stores ride across (T4). sched_barrier(0) per rule #18.
#define BARRIER() do {                                        \
    asm volatile("s_waitcnt lgkmcnt(0)" ::: "memory");        \
    __builtin_amdgcn_sched_barrier(0);                        \
    __builtin_amdgcn_s_barrier();                             \
    __builtin_amdgcn_sched_barrier(0);                        \
  } while (0)

__device__ __forceinline__ unsigned short f2bf(float f) {
  unsigned u = __builtin_bit_cast(unsigned, f);
  u += 0x7fffu + ((u >> 16) & 1u);          // round-to-nearest-even
  return (unsigned short)(u >> 16);
}

__device__ __forceinline__ unsigned long long pack4(float4 v) {
  return (unsigned long long)f2bf(v.x)
       | ((unsigned long long)f2bf(v.y) << 16)
       | ((unsigned long long)f2bf(v.z) << 32)
       | ((unsigned long long)f2bf(v.w) << 48);
}

__device__ __forceinline__ short8 load_wfrag(const float* p) {
  float4 a = *(const float4*)p;
  float4 b = *(const float4*)(p + 4);
  short8 r;
  r[0] = (short)f2bf(a.x); r[1] = (short)f2bf(a.y);
  r[2] = (short)f2bf(a.z); r[3] = (short)f2bf(a.w);
  r[4] = (short)f2bf(b.x); r[5] = (short)f2bf(b.y);
  r[6] = (short)f2bf(b.z); r[7] = (short)f2bf(b.w);
  return r;
}

__device__ __forceinline__ float fsigmoid(float x) {
  return __builtin_amdgcn_rcpf(1.0f + __expf(-x));
}
__device__ __forceinline__ float ftanh(float x) {
  return 1.0f - 2.0f * __builtin_amdgcn_rcpf(1.0f + __expf(2.0f * x));
}
// A&S 7.1.26 erf, max abs err 1.5e-7
__device__ __forceinline__ float ferf(float x) {
  float ax = fabsf(x);
  float t  = __builtin_amdgcn_rcpf(fmaf(0.3275911f, ax, 1.0f));
  float p  = fmaf(1.061405429f, t, -1.453152027f);
  p = fmaf(p, t, 1.421413741f);
  p = fmaf(p, t, -0.284496736f);
  p = fmaf(p, t, 0.254829592f);
  p = p * t;
  float y = 1.0f - p * __expf(-ax * ax);
  return copysignf(y, x);
}

// bias_t[t][j] = msg_b[j] + sum_d cos(t*freq[d]+phase[d]) * msg_W[j][128+d]
__global__ void bias_kernel(const float* __restrict__ msg_W,
                            const float* __restrict__ msg_b,
                            const float* __restrict__ freq,
                            const float* __restrict__ phase,
                            float* __restrict__ bias_t) {
  __shared__ float teL[DD];
  const int t = blockIdx.x;
  const int j = threadIdx.x;
  teL[j] = cosf(fmaf((float)t, freq[j], phase[j]));
  __syncthreads();
  float acc = msg_b[j];
  const float* wrow = msg_W + j * 192 + 128;
  #pragma unroll 8
  for (int k = 0; k < DD; ++k) acc = fmaf(teL[k], wrow[k], acc);
  bias_t[t * DD + j] = acc;
}

__launch_bounds__(BLK, 4)
__global__ void scan6(const float* __restrict__ x,
                      const int*   __restrict__ mask,
                      const float* __restrict__ msg_W,
                      const float* __restrict__ W_ih,
                      const float* __restrict__ W_hh,
                      const float* __restrict__ b_ih,
                      const float* __restrict__ b_hh,
                      const float* __restrict__ bias_t,
                      float* __restrict__ out) {
  // bf16 tiles: stride 72 shorts (144 B) -> <=2-way banks on b128 frag reads
  __shared__ alignas(16) unsigned short xs[16 * 72];
  __shared__ alignas(16) unsigned short ss[16 * 72];
  __shared__ alignas(16) unsigned short ms[16 * 72];
  __shared__ alignas(16) float s0a[16 * 68];   // fp32 state staging (G0 writes, G1 out-reads)
  __shared__ alignas(16) float ghl[16 * 260];  // gh transfer (also mean-scratch at init)
  __shared__ int tr_lds[TT + 2];

  const int tid  = threadIdx.x;
  const int lane = tid & 63;
  const int wv   = tid >> 6;
  const int grp  = wv >> 2;        // 0: msg/gi/gates chain, 1: gh + staging
  const int w4   = wv & 3;
  const int col  = lane & 15;
  const int kh   = lane >> 4;
  const int n    = w4 * 16 + col;  // output column this lane owns
  const int row0 = blockIdx.x * RV;

  if (tid < TT) tr_lds[tid] = tid * mask[tid];
  else if (tid < TT + 2) tr_lds[tid] = 0;

  // ---- group-specific weight fragments (registers, one-time) ----
  short8 wm[4], wi[3][2], wh[3][2];
  float bsum01[2] = {0.f, 0.f}, bih2 = 0.f, bhh2 = 0.f;
  if (grp == 0) {
    const float* mrow = msg_W + (size_t)n * 192;
    #pragma unroll
    for (int kf = 0; kf < 4; ++kf) wm[kf] = load_wfrag(mrow + kf * 32 + kh * 8);
    #pragma unroll
    for (int p = 0; p < 3; ++p) {
      const float* irow = W_ih + (size_t)(p * 64 + n) * 64;
      #pragma unroll
      for (int kf = 0; kf < 2; ++kf) wi[p][kf] = load_wfrag(irow + kf * 32 + kh * 8);
    }
    bsum01[0] = b_ih[n]      + b_hh[n];
    bsum01[1] = b_ih[64 + n] + b_hh[64 + n];
    bih2 = b_ih[128 + n];
    bhh2 = b_hh[128 + n];
  } else {
    #pragma unroll
    for (int p = 0; p < 3; ++p) {
      const float* hrow = W_hh + (size_t)(p * 64 + n) * 64;
      #pragma unroll
      for (int kf = 0; kf < 2; ++kf) wh[p][kf] = load_wfrag(hrow + kf * 32 + kh * 8);
    }
  }

  // ---- s0 = mean over t: 4 time-quarters x 128 float4-units (8 rows x 16) ----
  {
    const int q = tid >> 7, u = tid & 127;
    const int fr = u >> 4, fd = (u & 15) * 4;
    const float* px = x + ((size_t)(q * 64)) * (NROW * DD)
                        + (size_t)(row0 + fr) * DD + fd;
    float4 acc = {0.f, 0.f, 0.f, 0.f};
    #pragma unroll 4
    for (int tl = 0; tl < 64; ++tl) {
      float4 v = *(const float4*)(px + (size_t)tl * (NROW * DD));
      acc.x += v.x; acc.y += v.y; acc.z += v.z; acc.w += v.w;
    }
    *(float4*)&ghl[(q * 128 + u) * 4] = acc;   // ghl as scratch (pre-loop)
  }
  __syncthreads();
  if (tid < 128) {
    const int fr = tid >> 4, fd = (tid & 15) * 4;
    float4 a = *(const float4*)&ghl[tid * 4];
    float4 b = *(const float4*)&ghl[(128 + tid) * 4];
    float4 c = *(const float4*)&ghl[(256 + tid) * 4];
    float4 d = *(const float4*)&ghl[(384 + tid) * 4];
    const float inv = 1.0f / 256.0f;
    float4 m = { (a.x + b.x + c.x + d.x) * inv, (a.y + b.y + c.y + d.y) * inv,
                 (a.z + b.z + c.z + d.z) * inv, (a.w + b.w + c.w + d.w) * inv };
    *(float4*)&s0a[fr * 68 + fd] = m;
    *(unsigned long long*)&ss[fr * 72 + fd] = pack4(m);
    float4 xv0 = *(const float4*)(x + (size_t)(row0 + fr) * DD + fd);  // tr[0]=0
    *(unsigned long long*)&xs[fr * 72 + fd] = pack4(xv0);
  } else if (tid < 256) {
    // zero the unused tile rows 8..15 once (keeps garbage finite & deterministic)
    const int u2 = tid - 128;
    const int fr = 8 + (u2 >> 4), fd = (u2 & 15) * 4;
    float4 z = {0.f, 0.f, 0.f, 0.f};
    *(float4*)&s0a[fr * 68 + fd] = z;
    *(unsigned long long*)&ss[fr * 72 + fd] = 0ull;
    *(unsigned long long*)&xs[fr * 72 + fd] = 0ull;
  }
  __syncthreads();

  // G0: fp32 state registers + first msg bias
  float s_reg[4] = {0.f, 0.f, 0.f, 0.f};
  float btc = 0.f;
  if (grp == 0) {
    #pragma unroll
    for (int i = 0; i < 4; ++i) s_reg[i] = s0a[(kh * 4 + i) * 68 + n];
    btc = bias_t[n];                 // bias for t=0 (tr[0]=0)
    __builtin_amdgcn_s_setprio(1);   // critical-chain waves get priority
  }

  // G1 staging map: first 128 G1 threads cover 8 rows x 16 float4
  const int t1  = tid & 255;
  const int fr1 = t1 >> 4;           // valid when t1 < 128: 0..7
  const int fd1 = (t1 & 15) * 4;
  float4 xv = {0.f, 0.f, 0.f, 0.f};
  if (grp == 1 && t1 < 128)
    xv = *(const float4*)(x + ((size_t)tr_lds[1] * NROW + row0 + fr1) * DD + fd1);

  for (int t = 0; t < TT; ++t) {
    // ================= PHASE 1 =================
    if (grp == 0) {
      // msg = GELU( x-part + s-part + bias_t )  (two parallel 2-chains)
      const unsigned short* ax = &xs[(lane & 15) * 72];
      const unsigned short* as = &ss[(lane & 15) * 72];
      short8 xa0 = *(const short8*)(ax + kh * 8);
      short8 xa1 = *(const short8*)(ax + 32 + kh * 8);
      short8 sa0 = *(const short8*)(as + kh * 8);
      short8 sa1 = *(const short8*)(as + 32 + kh * 8);
      float btn = 0.f;
      if (t + 1 < TT) btn = bias_t[tr_lds[t + 1] * DD + n];  // next-step bias prefetch
      f32x4 amx = {0.f, 0.f, 0.f, 0.f};
      amx = __builtin_amdgcn_mfma_f32_16x16x32_bf16(xa0, wm[0], amx, 0, 0, 0);
      amx = __builtin_amdgcn_mfma_f32_16x16x32_bf16(xa1, wm[1], amx, 0, 0, 0);
      f32x4 ams = {0.f, 0.f, 0.f, 0.f};
      ams = __builtin_amdgcn_mfma_f32_16x16x32_bf16(sa0, wm[2], ams, 0, 0, 0);
      ams = __builtin_amdgcn_mfma_f32_16x16x32_bf16(sa1, wm[3], ams, 0, 0, 0);
      #pragma unroll
      for (int i = 0; i < 4; ++i) {
        float a = amx[i] + ams[i] + btc;
        float g = 0.5f * a * (1.0f + ferf(a * 0.70710678118654752f));
        ms[(kh * 4 + i) * 72 + n] = f2bf(g);
      }
      btc = btn;
    } else {
      // gh = s @ W_hh^T
      const unsigned short* as = &ss[(lane & 15) * 72];
      short8 sa0 = *(const short8*)(as + kh * 8);
      short8 sa1 = *(const short8*)(as + 32 + kh * 8);
      f32x4 agh[3];
      #pragma unroll
      for (int p = 0; p < 3; ++p) {
        f32x4 c = {0.f, 0.f, 0.f, 0.f};
        c = __builtin_amdgcn_mfma_f32_16x16x32_bf16(sa0, wh[p][0], c, 0, 0, 0);
        c = __builtin_amdgcn_mfma_f32_16x16x32_bf16(sa1, wh[p][1], c, 0, 0, 0);
        agh[p] = c;
      }
      #pragma unroll
      for (int i = 0; i < 4; ++i) {
        float4 gv = { agh[0][i], agh[1][i], agh[2][i], 0.f };
        *(float4*)&ghl[(kh * 4 + i) * 260 + n * 4] = gv;
      }
      // out-write of t-1 (s0a stable: written ph2(t-1), rewritten ph2(t))
      if (t > 0 && t1 < 128) {
        float4 ov = *(const float4*)&s0a[fr1 * 68 + fd1];
        *(float4*)(out + ((size_t)(t - 1) * NROW + row0 + fr1) * DD + fd1) = ov;
      }
    }
    BARRIER();  // B1: ms & ghl visible; xs/ss reads of this phase done

    // ================= PHASE 2 =================
    if (grp == 0) {
      const unsigned short* am = &ms[(lane & 15) * 72];
      short8 ma0 = *(const short8*)(am + kh * 8);
      short8 ma1 = *(const short8*)(am + 32 + kh * 8);
      f32x4 agi[3];
      #pragma unroll
      for (int p = 0; p < 3; ++p) {
        f32x4 c = {0.f, 0.f, 0.f, 0.f};
        c = __builtin_amdgcn_mfma_f32_16x16x32_bf16(ma0, wi[p][0], c, 0, 0, 0);
        c = __builtin_amdgcn_mfma_f32_16x16x32_bf16(ma1, wi[p][1], c, 0, 0, 0);
        agi[p] = c;
      }
      #pragma unroll
      for (int i = 0; i < 4; ++i) {
        const int rr = kh * 4 + i;
        float4 gh4 = *(const float4*)&ghl[rr * 260 + n * 4];
        float gr  = agi[0][i] + gh4.x + bsum01[0];
        float gz  = agi[1][i] + gh4.y + bsum01[1];
        float gni = agi[2][i] + bih2;
        float gnh = gh4.z + bhh2;
        float rg = fsigmoid(gr);
        float zg = fsigmoid(gz);
        float ng = ftanh(fmaf(rg, gnh, gni));
        float sn = fmaf(zg, s_reg[i] - ng, ng);
        s_reg[i] = sn;
        ss[rr * 72 + n]  = f2bf(sn);
        s0a[rr * 68 + n] = sn;
      }
    } else {
      // stage xs(t+1) from xv (loaded a full step ago), refill xv for t+2
      if (t1 < 128) {
        if (t + 1 < TT)
          *(unsigned long long*)&xs[fr1 * 72 + fd1] = pack4(xv);
        if (t + 2 < TT)
          xv = *(const float4*)(x + ((size_t)tr_lds[t + 2] * NROW + row0 + fr1) * DD + fd1);
      }
    }
    BARRIER();  // B2: ss/s0a/xs updated for next step
  }

  // final output row (t = 255); s0a visible after last B2
  if (grp == 1 && t1 < 128) {
    float4 ov = *(const float4*)&s0a[fr1 * 68 + fd1];
    *(float4*)(out + ((size_t)(TT - 1) * NROW + row0 + fr1) * DD + fd1) = ov;
  }
}

extern "C" void kernel_launch(void* const* d_in, const int* in_sizes, int n_in,
                              void* d_out, int out_size, void* d_ws, size_t ws_size,
                              hipStream_t stream) {
  const float* x      = (const float*)d_in[0];
  const int*   mask   = (const int*)  d_in[1];
  const float* msg_W  = (const float*)d_in[2];
  const float* msg_b  = (const float*)d_in[3];
  const float* W_ih   = (const float*)d_in[4];
  const float* W_hh   = (const float*)d_in[5];
  const float* b_ih   = (const float*)d_in[6];
  const float* b_hh   = (const float*)d_in[7];
  const float* freq   = (const float*)d_in[8];
  const float* phase  = (const float*)d_in[9];
  float* out    = (float*)d_out;
  float* bias_t = (float*)d_ws;   // TT*DD floats = 64 KB

  (void)in_sizes; (void)n_in; (void)out_size; (void)ws_size;

  bias_kernel<<<TT, DD, 0, stream>>>(msg_W, msg_b, freq, phase, bias_t);
  scan6<<<GRID, BLK, 0, stream>>>(x, mask, msg_W, W_ih, W_hh,
                                  b_ih, b_hh, bias_t, out);
}

// Round 7
// 345.301 us; speedup vs baseline: 1.0935x; 1.0935x over previous
//
#include <hip/hip_runtime.h>
#include <math.h>

#define DD    64
#define TT    256
#define NROW  4096
#define BLK   512
#define GRID  256          // 256 row-tiles of 16, 1 block/CU

typedef __attribute__((ext_vector_type(8))) short  short8;
typedef __attribute__((ext_vector_type(4))) float  f32x4;

// Raw workgroup barrier: LDS visibility only (lgkmcnt), no vmcnt drain.
// Global loads/stores ride across (T4). sched_barrier(0) per rule #18.
#define BARRIER() do {                                        \
    asm volatile("s_waitcnt lgkmcnt(0)" ::: "memory");        \
    __builtin_amdgcn_sched_barrier(0);                        \
    __builtin_amdgcn_s_barrier();                             \
    __builtin_amdgcn_sched_barrier(0);                        \
  } while (0)

__device__ __forceinline__ unsigned short f2bf(float f) {
  unsigned u = __builtin_bit_cast(unsigned, f);
  u += 0x7fffu + ((u >> 16) & 1u);          // round-to-nearest-even
  return (unsigned short)(u >> 16);
}

__device__ __forceinline__ unsigned long long pack4(f32x4 v) {
  return (unsigned long long)f2bf(v[0])
       | ((unsigned long long)f2bf(v[1]) << 16)
       | ((unsigned long long)f2bf(v[2]) << 32)
       | ((unsigned long long)f2bf(v[3]) << 48);
}

__device__ __forceinline__ short8 pack_frag(f32x4 a, f32x4 b) {
  short8 r;
  r[0] = (short)f2bf(a[0]); r[1] = (short)f2bf(a[1]);
  r[2] = (short)f2bf(a[2]); r[3] = (short)f2bf(a[3]);
  r[4] = (short)f2bf(b[0]); r[5] = (short)f2bf(b[1]);
  r[6] = (short)f2bf(b[2]); r[7] = (short)f2bf(b[3]);
  return r;
}

__device__ __forceinline__ short8 load_wfrag(const float* p) {
  f32x4 a = *(const f32x4*)p;
  f32x4 b = *(const f32x4*)(p + 4);
  return pack_frag(a, b);
}

__device__ __forceinline__ float fsigmoid(float x) {
  return __builtin_amdgcn_rcpf(1.0f + __expf(-x));
}
__device__ __forceinline__ float ftanh(float x) {
  return 1.0f - 2.0f * __builtin_amdgcn_rcpf(1.0f + __expf(2.0f * x));
}
// A&S 7.1.26 erf, max abs err 1.5e-7
__device__ __forceinline__ float ferf(float x) {
  float ax = fabsf(x);
  float t  = __builtin_amdgcn_rcpf(fmaf(0.3275911f, ax, 1.0f));
  float p  = fmaf(1.061405429f, t, -1.453152027f);
  p = fmaf(p, t, 1.421413741f);
  p = fmaf(p, t, -0.284496736f);
  p = fmaf(p, t, 0.254829592f);
  p = p * t;
  float y = 1.0f - p * __expf(-ax * ax);
  return copysignf(y, x);
}

// bias_t[t][j] = msg_b[j] + sum_d cos(t*freq[d]+phase[d]) * msg_W[j][128+d]
__global__ void bias_kernel(const float* __restrict__ msg_W,
                            const float* __restrict__ msg_b,
                            const float* __restrict__ freq,
                            const float* __restrict__ phase,
                            float* __restrict__ bias_t) {
  __shared__ float teL[DD];
  const int t = blockIdx.x;
  const int j = threadIdx.x;
  teL[j] = cosf(fmaf((float)t, freq[j], phase[j]));
  __syncthreads();
  float acc = msg_b[j];
  const float* wrow = msg_W + j * 192 + 128;
  #pragma unroll 8
  for (int k = 0; k < DD; ++k) acc = fmaf(teL[k], wrow[k], acc);
  bias_t[t * DD + j] = acc;
}

__launch_bounds__(BLK, 1)
__global__ void scan7(const float* __restrict__ x,
                      const int*   __restrict__ mask,
                      const float* __restrict__ msg_W,
                      const float* __restrict__ W_ih,
                      const float* __restrict__ W_hh,
                      const float* __restrict__ b_ih,
                      const float* __restrict__ b_hh,
                      const float* __restrict__ bias_t,
                      float* __restrict__ out) {
  // bf16 tiles: stride 72 shorts (144 B) -> <=2-way banks on b128 frag reads
  __shared__ alignas(16) unsigned short ss[16 * 72];
  __shared__ alignas(16) unsigned short ms[16 * 72];
  __shared__ alignas(16) float amxl[64 * 20];  // x-part+bias of msg pre-act: [n][rr], b128 rw
  __shared__ alignas(16) float ghl[16 * 260];  // gh transfer [rr][n*4+{r,z,n,pad}] (+mean scratch)
  __shared__ alignas(16) float s0a[16 * 68];   // fp32 state staging (G0 writes, G1 out-reads)
  __shared__ int tr_lds[TT];

  const int tid  = threadIdx.x;
  const int lane = tid & 63;
  const int wv   = tid >> 6;
  const int grp  = wv >> 2;        // 0: msg(s-part)/gi/gates chain, 1: gh + amx + staging
  const int w4   = wv & 3;
  const int col  = lane & 15;
  const int kh   = lane >> 4;
  const int n    = w4 * 16 + col;  // output column this lane owns
  const int row0 = blockIdx.x * 16;

  if (tid < TT) tr_lds[tid] = tid * mask[tid];

  // ---- group-specific weight fragments (registers, one-time) ----
  short8 ws[2], wi[3][2], wh[3][2], wx[2];
  float bsum01[2] = {0.f, 0.f}, bih2 = 0.f, bhh2 = 0.f;
  if (grp == 0) {
    const float* mrow = msg_W + (size_t)n * 192;
    ws[0] = load_wfrag(mrow + 64 + kh * 8);     // s-part k 0..31
    ws[1] = load_wfrag(mrow + 96 + kh * 8);     // s-part k 32..63
    #pragma unroll
    for (int p = 0; p < 3; ++p) {
      const float* irow = W_ih + (size_t)(p * 64 + n) * 64;
      #pragma unroll
      for (int kf = 0; kf < 2; ++kf) wi[p][kf] = load_wfrag(irow + kf * 32 + kh * 8);
    }
    bsum01[0] = b_ih[n]      + b_hh[n];
    bsum01[1] = b_ih[64 + n] + b_hh[64 + n];
    bih2 = b_ih[128 + n];
    bhh2 = b_hh[128 + n];
  } else {
    const float* mrow = msg_W + (size_t)n * 192;
    wx[0] = load_wfrag(mrow + kh * 8);          // x-part k 0..31
    wx[1] = load_wfrag(mrow + 32 + kh * 8);     // x-part k 32..63
    #pragma unroll
    for (int p = 0; p < 3; ++p) {
      const float* hrow = W_hh + (size_t)(p * 64 + n) * 64;
      #pragma unroll
      for (int kf = 0; kf < 2; ++kf) wh[p][kf] = load_wfrag(hrow + kf * 32 + kh * 8);
    }
  }

  // ---- s0 = mean over t (512 threads: 2 time-halves x 16 rows x 16 float4) ----
  {
    const int half = tid >> 8, rem = tid & 255;
    const int fr = rem >> 4, fd = (rem & 15) * 4;
    const float* px = x + ((size_t)half * 128) * (NROW * DD)
                        + (size_t)(row0 + fr) * DD + fd;
    f32x4 acc = {0.f, 0.f, 0.f, 0.f};
    #pragma unroll 4
    for (int tl = 0; tl < 128; ++tl) {
      f32x4 v = *(const f32x4*)(px + (size_t)tl * (NROW * DD));
      acc += v;
    }
    *(f32x4*)&ghl[tid * 4] = acc;   // ghl as scratch (pre-loop); tid*4+3 < 2048 < 4160
  }
  __syncthreads();
  if (tid < 256) {
    const int fr = tid >> 4, fd = (tid & 15) * 4;
    f32x4 a = *(const f32x4*)&ghl[tid * 4];
    f32x4 b = *(const f32x4*)&ghl[(256 + tid) * 4];
    f32x4 m = (a + b) * (1.0f / 256.0f);
    *(f32x4*)&s0a[fr * 68 + fd] = m;
    *(unsigned long long*)&ss[fr * 72 + fd] = pack4(m);
  }

  // ---- G1 init: amx(0)+bias(0) into amxl; preload x(tr[1]) frags into regs ----
  f32x4 xva = {0,0,0,0}, xvb = {0,0,0,0}, xvc = {0,0,0,0}, xvd = {0,0,0,0};
  if (grp == 1) {
    const float* px0 = x + (size_t)(row0 + (lane & 15)) * DD + kh * 8;  // tr[0]=0
    f32x4 f0a = *(const f32x4*)(px0);
    f32x4 f0b = *(const f32x4*)(px0 + 4);
    f32x4 f1a = *(const f32x4*)(px0 + 32);
    f32x4 f1b = *(const f32x4*)(px0 + 36);
    short8 xa0 = pack_frag(f0a, f0b);
    short8 xa1 = pack_frag(f1a, f1b);
    f32x4 c = {0.f, 0.f, 0.f, 0.f};
    c = __builtin_amdgcn_mfma_f32_16x16x32_bf16(xa0, wx[0], c, 0, 0, 0);
    c = __builtin_amdgcn_mfma_f32_16x16x32_bf16(xa1, wx[1], c, 0, 0, 0);
    const float bt = bias_t[n];
    c[0] += bt; c[1] += bt; c[2] += bt; c[3] += bt;
    *(f32x4*)&amxl[n * 20 + kh * 4] = c;
    const float* px1 = x + ((size_t)tr_lds[1] * NROW + row0 + (lane & 15)) * DD + kh * 8;
    xva = *(const f32x4*)(px1);
    xvb = *(const f32x4*)(px1 + 4);
    xvc = *(const f32x4*)(px1 + 32);
    xvd = *(const f32x4*)(px1 + 36);
  }
  __syncthreads();

  // G0: fp32 state registers
  float s_reg[4] = {0.f, 0.f, 0.f, 0.f};
  if (grp == 0) {
    #pragma unroll
    for (int i = 0; i < 4; ++i) s_reg[i] = s0a[(kh * 4 + i) * 68 + n];
    __builtin_amdgcn_s_setprio(1);   // critical-chain waves get priority
  }

  // G1 staging map: 256 threads cover 16 rows x 16 float4
  const int t1  = tid & 255;
  const int fr1 = t1 >> 4;
  const int fd1 = (t1 & 15) * 4;

  for (int t = 0; t < TT; ++t) {
    // ================= PHASE 1 =================
    if (grp == 0) {
      // msg pre-act = s-part MFMA + (x-part + bias) from amxl; then GELU
      const unsigned short* as = &ss[(lane & 15) * 72];
      short8 sa0 = *(const short8*)(as + kh * 8);
      short8 sa1 = *(const short8*)(as + 32 + kh * 8);
      f32x4 am4 = *(const f32x4*)&amxl[n * 20 + kh * 4];
      f32x4 ams = {0.f, 0.f, 0.f, 0.f};
      ams = __builtin_amdgcn_mfma_f32_16x16x32_bf16(sa0, ws[0], ams, 0, 0, 0);
      ams = __builtin_amdgcn_mfma_f32_16x16x32_bf16(sa1, ws[1], ams, 0, 0, 0);
      #pragma unroll
      for (int i = 0; i < 4; ++i) {
        float a = ams[i] + am4[i];
        float g = 0.5f * a * (1.0f + ferf(a * 0.70710678118654752f));
        ms[(kh * 4 + i) * 72 + n] = f2bf(g);
      }
    } else {
      // gh = s @ W_hh^T
      const unsigned short* as = &ss[(lane & 15) * 72];
      short8 sa0 = *(const short8*)(as + kh * 8);
      short8 sa1 = *(const short8*)(as + 32 + kh * 8);
      f32x4 agh[3];
      #pragma unroll
      for (int p = 0; p < 3; ++p) {
        f32x4 c = {0.f, 0.f, 0.f, 0.f};
        c = __builtin_amdgcn_mfma_f32_16x16x32_bf16(sa0, wh[p][0], c, 0, 0, 0);
        c = __builtin_amdgcn_mfma_f32_16x16x32_bf16(sa1, wh[p][1], c, 0, 0, 0);
        agh[p] = c;
      }
      #pragma unroll
      for (int i = 0; i < 4; ++i) {
        f32x4 gv = { agh[0][i], agh[1][i], agh[2][i], 0.f };
        *(f32x4*)&ghl[(kh * 4 + i) * 260 + n * 4] = gv;
      }
      // out-write of t-1 from s0a (read drains at B1, before G0 rewrites)
      if (t > 0) {
        f32x4 ov = *(const f32x4*)&s0a[fr1 * 68 + fd1];
        *(f32x4*)(out + ((size_t)(t - 1) * NROW + row0 + fr1) * DD + fd1) = ov;
      }
    }
    BARRIER();  // B1: ms & ghl visible; ss/amxl/s0a reads of phase 1 done

    // ================= PHASE 2 =================
    if (grp == 0) {
      // hoisted ghl reads (latency hides under gi MFMAs)
      f32x4 gh4[4];
      #pragma unroll
      for (int i = 0; i < 4; ++i)
        gh4[i] = *(const f32x4*)&ghl[(kh * 4 + i) * 260 + n * 4];
      const unsigned short* am = &ms[(lane & 15) * 72];
      short8 ma0 = *(const short8*)(am + kh * 8);
      short8 ma1 = *(const short8*)(am + 32 + kh * 8);
      f32x4 agi[3];
      #pragma unroll
      for (int p = 0; p < 3; ++p) {
        f32x4 c = {0.f, 0.f, 0.f, 0.f};
        c = __builtin_amdgcn_mfma_f32_16x16x32_bf16(ma0, wi[p][0], c, 0, 0, 0);
        c = __builtin_amdgcn_mfma_f32_16x16x32_bf16(ma1, wi[p][1], c, 0, 0, 0);
        agi[p] = c;
      }
      #pragma unroll
      for (int i = 0; i < 4; ++i) {
        const int rr = kh * 4 + i;
        float gr  = agi[0][i] + gh4[i][0] + bsum01[0];
        float gz  = agi[1][i] + gh4[i][1] + bsum01[1];
        float gni = agi[2][i] + bih2;
        float gnh = gh4[i][2] + bhh2;
        float rg = fsigmoid(gr);
        float zg = fsigmoid(gz);
        float ng = ftanh(fmaf(rg, gnh, gni));
        float sn = fmaf(zg, s_reg[i] - ng, ng);
        s_reg[i] = sn;
        ss[rr * 72 + n]  = f2bf(sn);
        s0a[rr * 68 + n] = sn;
      }
    } else {
      // amx(t+1) = x(tr[t+1])-part + bias(t+1), from regs loaded a full step ago
      if (t + 1 < TT) {
        float bt = bias_t[tr_lds[t + 1] * DD + n];
        short8 xa0 = pack_frag(xva, xvb);
        short8 xa1 = pack_frag(xvc, xvd);
        f32x4 c = {0.f, 0.f, 0.f, 0.f};
        c = __builtin_amdgcn_mfma_f32_16x16x32_bf16(xa0, wx[0], c, 0, 0, 0);
        c = __builtin_amdgcn_mfma_f32_16x16x32_bf16(xa1, wx[1], c, 0, 0, 0);
        c[0] += bt; c[1] += bt; c[2] += bt; c[3] += bt;
        *(f32x4*)&amxl[n * 20 + kh * 4] = c;
      }
      // refill x frag regs for t+2 (full-step latency cover)
      if (t + 2 < TT) {
        const float* pxn = x + ((size_t)tr_lds[t + 2] * NROW + row0 + (lane & 15)) * DD + kh * 8;
        xva = *(const f32x4*)(pxn);
        xvb = *(const f32x4*)(pxn + 4);
        xvc = *(const f32x4*)(pxn + 32);
        xvd = *(const f32x4*)(pxn + 36);
      }
    }
    BARRIER();  // B2: ss/s0a/amxl updated for next step
  }

  // final output row (t = 255); s0a visible after last B2
  if (grp == 1) {
    f32x4 ov = *(const f32x4*)&s0a[fr1 * 68 + fd1];
    *(f32x4*)(out + ((size_t)(TT - 1) * NROW + row0 + fr1) * DD + fd1) = ov;
  }
}

extern "C" void kernel_launch(void* const* d_in, const int* in_sizes, int n_in,
                              void* d_out, int out_size, void* d_ws, size_t ws_size,
                              hipStream_t stream) {
  const float* x      = (const float*)d_in[0];
  const int*   mask   = (const int*)  d_in[1];
  const float* msg_W  = (const float*)d_in[2];
  const float* msg_b  = (const float*)d_in[3];
  const float* W_ih   = (const float*)d_in[4];
  const float* W_hh   = (const float*)d_in[5];
  const float* b_ih   = (const float*)d_in[6];
  const float* b_hh   = (const float*)d_in[7];
  const float* freq   = (const float*)d_in[8];
  const float* phase  = (const float*)d_in[9];
  float* out    = (float*)d_out;
  float* bias_t = (float*)d_ws;   // TT*DD floats = 64 KB

  (void)in_sizes; (void)n_in; (void)out_size; (void)ws_size;

  bias_kernel<<<TT, DD, 0, stream>>>(msg_W, msg_b, freq, phase, bias_t);
  scan7<<<GRID, BLK, 0, stream>>>(x, mask, msg_W, W_ih, W_hh,
                                  b_ih, b_hh, bias_t, out);
}

// Round 8
// 311.328 us; speedup vs baseline: 1.2128x; 1.1091x over previous
//
#include <hip/hip_runtime.h>
#include <math.h>

#define DD    64
#define TT    256
#define NROW  4096
#define BLK   512
#define GRID  256          // 256 row-tiles of 16, 1 block/CU

typedef __attribute__((ext_vector_type(8))) short  short8;
typedef __attribute__((ext_vector_type(4))) float  f32x4;

// Raw workgroup barrier: LDS visibility only (lgkmcnt drain), no vmcnt drain.
// Global loads/stores ride across (T4). sched_barrier(0) per rule #18.
#define BARRIER() do {                                        \
    asm volatile("s_waitcnt lgkmcnt(0)" ::: "memory");        \
    __builtin_amdgcn_sched_barrier(0);                        \
    __builtin_amdgcn_s_barrier();                             \
    __builtin_amdgcn_sched_barrier(0);                        \
  } while (0)

__device__ __forceinline__ unsigned short f2bf(float f) {
  unsigned u = __builtin_bit_cast(unsigned, f);
  u += 0x7fffu + ((u >> 16) & 1u);          // round-to-nearest-even
  return (unsigned short)(u >> 16);
}

__device__ __forceinline__ unsigned long long pack4(f32x4 v) {
  return (unsigned long long)f2bf(v[0])
       | ((unsigned long long)f2bf(v[1]) << 16)
       | ((unsigned long long)f2bf(v[2]) << 32)
       | ((unsigned long long)f2bf(v[3]) << 48);
}

__device__ __forceinline__ short8 pack_frag(f32x4 a, f32x4 b) {
  short8 r;
  r[0] = (short)f2bf(a[0]); r[1] = (short)f2bf(a[1]);
  r[2] = (short)f2bf(a[2]); r[3] = (short)f2bf(a[3]);
  r[4] = (short)f2bf(b[0]); r[5] = (short)f2bf(b[1]);
  r[6] = (short)f2bf(b[2]); r[7] = (short)f2bf(b[3]);
  return r;
}

__device__ __forceinline__ short8 load_wfrag(const float* p) {
  f32x4 a = *(const f32x4*)p;
  f32x4 b = *(const f32x4*)(p + 4);
  return pack_frag(a, b);
}

__device__ __forceinline__ float fsigmoid(float x) {
  return __builtin_amdgcn_rcpf(1.0f + __expf(-x));
}
__device__ __forceinline__ float ftanh(float x) {
  return 1.0f - 2.0f * __builtin_amdgcn_rcpf(1.0f + __expf(2.0f * x));
}
// A&S 7.1.26 erf, max abs err 1.5e-7
__device__ __forceinline__ float ferf(float x) {
  float ax = fabsf(x);
  float t  = __builtin_amdgcn_rcpf(fmaf(0.3275911f, ax, 1.0f));
  float p  = fmaf(1.061405429f, t, -1.453152027f);
  p = fmaf(p, t, 1.421413741f);
  p = fmaf(p, t, -0.284496736f);
  p = fmaf(p, t, 0.254829592f);
  p = p * t;
  float y = 1.0f - p * __expf(-ax * ax);
  return copysignf(y, x);
}

// bias_t[t][j] = msg_b[j] + sum_d cos(t*freq[d]+phase[d]) * msg_W[j][128+d]
__global__ void bias_kernel(const float* __restrict__ msg_W,
                            const float* __restrict__ msg_b,
                            const float* __restrict__ freq,
                            const float* __restrict__ phase,
                            float* __restrict__ bias_t) {
  __shared__ float teL[DD];
  const int t = blockIdx.x;
  const int j = threadIdx.x;
  teL[j] = cosf(fmaf((float)t, freq[j], phase[j]));
  __syncthreads();
  float acc = msg_b[j];
  const float* wrow = msg_W + j * 192 + 128;
  #pragma unroll 8
  for (int k = 0; k < DD; ++k) acc = fmaf(teL[k], wrow[k], acc);
  bias_t[t * DD + j] = acc;
}

__launch_bounds__(BLK, 1)
__global__ void scan8(const float* __restrict__ x,
                      const int*   __restrict__ mask,
                      const float* __restrict__ msg_W,
                      const float* __restrict__ W_ih,
                      const float* __restrict__ W_hh,
                      const float* __restrict__ b_ih,
                      const float* __restrict__ b_hh,
                      const float* __restrict__ bias_t,
                      float* __restrict__ out) {
  // bf16 tiles: stride 72 shorts (144 B) -> <=2-way banks on b128 frag reads
  __shared__ alignas(16) unsigned short xs[16 * 72];
  __shared__ alignas(16) unsigned short ss[16 * 72];
  __shared__ alignas(16) unsigned short ms[16 * 72];
  __shared__ alignas(16) float s0a[16 * 68];   // fp32 state staging (G0 writes, G1 out-reads)
  __shared__ alignas(16) float ghl[16 * 260];  // gh transfer [rr][n*4+{r,z,n,pad}] (+mean scratch)
  __shared__ int tr_lds[TT];

  const int tid  = threadIdx.x;
  const int lane = tid & 63;
  const int wv   = tid >> 6;
  const int grp  = wv >> 2;        // 0: msg/gi/gates chain, 1: gh + staging
  const int w4   = wv & 3;
  const int col  = lane & 15;
  const int kh   = lane >> 4;
  const int n    = w4 * 16 + col;  // output column this lane owns
  const int row0 = blockIdx.x * 16;

  if (tid < TT) tr_lds[tid] = tid * mask[tid];

  // ---- group-specific weight fragments (registers, one-time) ----
  short8 wm[4], wi[3][2], wh[3][2];
  float bsum01[2] = {0.f, 0.f}, bih2 = 0.f, bhh2 = 0.f;
  if (grp == 0) {
    const float* mrow = msg_W + (size_t)n * 192;
    #pragma unroll
    for (int kf = 0; kf < 4; ++kf) wm[kf] = load_wfrag(mrow + kf * 32 + kh * 8);
    #pragma unroll
    for (int p = 0; p < 3; ++p) {
      const float* irow = W_ih + (size_t)(p * 64 + n) * 64;
      #pragma unroll
      for (int kf = 0; kf < 2; ++kf) wi[p][kf] = load_wfrag(irow + kf * 32 + kh * 8);
    }
    bsum01[0] = b_ih[n]      + b_hh[n];
    bsum01[1] = b_ih[64 + n] + b_hh[64 + n];
    bih2 = b_ih[128 + n];
    bhh2 = b_hh[128 + n];
  } else {
    #pragma unroll
    for (int p = 0; p < 3; ++p) {
      const float* hrow = W_hh + (size_t)(p * 64 + n) * 64;
      #pragma unroll
      for (int kf = 0; kf < 2; ++kf) wh[p][kf] = load_wfrag(hrow + kf * 32 + kh * 8);
    }
  }

  // ---- s0 = mean over t (512 threads: 2 time-halves x 16 rows x 16 float4) ----
  {
    const int half = tid >> 8, rem = tid & 255;
    const int fr = rem >> 4, fd = (rem & 15) * 4;
    const float* px = x + ((size_t)half * 128) * (NROW * DD)
                        + (size_t)(row0 + fr) * DD + fd;
    f32x4 acc = {0.f, 0.f, 0.f, 0.f};
    #pragma unroll 4
    for (int tl = 0; tl < 128; ++tl) {
      f32x4 v = *(const f32x4*)(px + (size_t)tl * (NROW * DD));
      acc += v;
    }
    float* dst = (half == 0) ? &s0a[(rem >> 4) * 68 + fd] : &ghl[rem * 4];
    *(f32x4*)dst = acc;
  }
  __syncthreads();
  if (tid < 256) {
    const int fr = tid >> 4, fd = (tid & 15) * 4;
    f32x4 a = *(const f32x4*)&s0a[fr * 68 + fd];
    f32x4 b = *(const f32x4*)&ghl[tid * 4];
    f32x4 m = (a + b) * (1.0f / 256.0f);
    *(f32x4*)&s0a[fr * 68 + fd] = m;
    *(unsigned long long*)&ss[fr * 72 + fd] = pack4(m);
    f32x4 xv0 = *(const f32x4*)(x + (size_t)(row0 + fr) * DD + fd);  // tr[0]=0
    *(unsigned long long*)&xs[fr * 72 + fd] = pack4(xv0);
  }
  __syncthreads();

  // G0: fp32 state registers + bias for t=0
  float s_reg[4] = {0.f, 0.f, 0.f, 0.f};
  float btc = 0.f;
  if (grp == 0) {
    #pragma unroll
    for (int i = 0; i < 4; ++i) s_reg[i] = s0a[(kh * 4 + i) * 68 + n];
    btc = bias_t[n];                 // tr[0] = 0
    __builtin_amdgcn_s_setprio(1);   // critical-chain waves get priority
  }

  // G1 staging map: 256 threads cover 16 rows x 16 float4
  const int t1  = tid & 255;
  const int fr1 = t1 >> 4;
  const int fd1 = (t1 & 15) * 4;

  // 2-deep x pipeline: xvA/xvB hold x(tr[t+1]), x(tr[t+2]) as f32x4/thread.
  f32x4 xvA = {0.f, 0.f, 0.f, 0.f}, xvB = {0.f, 0.f, 0.f, 0.f};
  if (grp == 1)
    xvA = *(const f32x4*)(x + ((size_t)tr_lds[1] * NROW + row0 + fr1) * DD + fd1);

  // One timestep. xv_use = x(tr[t+1]) (written to xs in ph2);
  // xv_load receives x(tr[t+2]) (issued in ph1, consumed ph2 of t+1).
  auto body = [&](int t, f32x4& xv_use, f32x4& xv_load) {
    // ================= PHASE 1 =================
    if (grp == 0) {
      const unsigned short* ax = &xs[(lane & 15) * 72];
      const unsigned short* as = &ss[(lane & 15) * 72];
      short8 xa0 = *(const short8*)(ax + kh * 8);
      short8 xa1 = *(const short8*)(ax + 32 + kh * 8);
      short8 sa0 = *(const short8*)(as + kh * 8);
      short8 sa1 = *(const short8*)(as + 32 + kh * 8);
      float btn = 0.f;
      if (t + 1 < TT) btn = bias_t[tr_lds[t + 1] * DD + n];  // 1-step-ahead (L2)
      f32x4 amx = {0.f, 0.f, 0.f, 0.f};
      amx = __builtin_amdgcn_mfma_f32_16x16x32_bf16(xa0, wm[0], amx, 0, 0, 0);
      amx = __builtin_amdgcn_mfma_f32_16x16x32_bf16(xa1, wm[1], amx, 0, 0, 0);
      f32x4 ams = {0.f, 0.f, 0.f, 0.f};
      ams = __builtin_amdgcn_mfma_f32_16x16x32_bf16(sa0, wm[2], ams, 0, 0, 0);
      ams = __builtin_amdgcn_mfma_f32_16x16x32_bf16(sa1, wm[3], ams, 0, 0, 0);
      #pragma unroll
      for (int i = 0; i < 4; ++i) {
        float a = amx[i] + ams[i] + btc;
        float g = 0.5f * a * (1.0f + ferf(a * 0.70710678118654752f));
        ms[(kh * 4 + i) * 72 + n] = f2bf(g);
      }
      btc = btn;
    } else {
      // gh = s @ W_hh^T
      const unsigned short* as = &ss[(lane & 15) * 72];
      short8 sa0 = *(const short8*)(as + kh * 8);
      short8 sa1 = *(const short8*)(as + 32 + kh * 8);
      f32x4 agh[3];
      #pragma unroll
      for (int p = 0; p < 3; ++p) {
        f32x4 c = {0.f, 0.f, 0.f, 0.f};
        c = __builtin_amdgcn_mfma_f32_16x16x32_bf16(sa0, wh[p][0], c, 0, 0, 0);
        c = __builtin_amdgcn_mfma_f32_16x16x32_bf16(sa1, wh[p][1], c, 0, 0, 0);
        agh[p] = c;
      }
      #pragma unroll
      for (int i = 0; i < 4; ++i) {
        f32x4 gv = { agh[0][i], agh[1][i], agh[2][i], 0.f };
        *(f32x4*)&ghl[(kh * 4 + i) * 260 + n * 4] = gv;
      }
      // out-write of t-1 from s0a (ds_read drains at B1, before G0 rewrites)
      if (t > 0) {
        f32x4 ov = *(const f32x4*)&s0a[fr1 * 68 + fd1];
        *(f32x4*)(out + ((size_t)(t - 1) * NROW + row0 + fr1) * DD + fd1) = ov;
      }
      // issue x(tr[t+2]) load; consumed in ph2 of t+1 (~1.3 steps of cover)
      if (t + 2 < TT)
        xv_load = *(const f32x4*)(x + ((size_t)tr_lds[t + 2] * NROW + row0 + fr1) * DD + fd1);
    }
    BARRIER();  // B1: ms & ghl visible; xs/ss/s0a reads of phase 1 done

    // ================= PHASE 2 =================
    if (grp == 0) {
      f32x4 gh4[4];
      #pragma unroll
      for (int i = 0; i < 4; ++i)
        gh4[i] = *(const f32x4*)&ghl[(kh * 4 + i) * 260 + n * 4];
      const unsigned short* am = &ms[(lane & 15) * 72];
      short8 ma0 = *(const short8*)(am + kh * 8);
      short8 ma1 = *(const short8*)(am + 32 + kh * 8);
      f32x4 agi[3];
      #pragma unroll
      for (int p = 0; p < 3; ++p) {
        f32x4 c = {0.f, 0.f, 0.f, 0.f};
        c = __builtin_amdgcn_mfma_f32_16x16x32_bf16(ma0, wi[p][0], c, 0, 0, 0);
        c = __builtin_amdgcn_mfma_f32_16x16x32_bf16(ma1, wi[p][1], c, 0, 0, 0);
        agi[p] = c;
      }
      #pragma unroll
      for (int i = 0; i < 4; ++i) {
        const int rr = kh * 4 + i;
        float gr  = agi[0][i] + gh4[i][0] + bsum01[0];
        float gz  = agi[1][i] + gh4[i][1] + bsum01[1];
        float gni = agi[2][i] + bih2;
        float gnh = gh4[i][2] + bhh2;
        float rg = fsigmoid(gr);
        float zg = fsigmoid(gz);
        float ng = ftanh(fmaf(rg, gnh, gni));
        float sn = fmaf(zg, s_reg[i] - ng, ng);
        s_reg[i] = sn;
        ss[rr * 72 + n]  = f2bf(sn);
        s0a[rr * 68 + n] = sn;
      }
    } else {
      // stage xs(t+1) from xv_use (loaded in ph1 of t-1; long since arrived)
      if (t + 1 < TT)
        *(unsigned long long*)&xs[fr1 * 72 + fd1] = pack4(xv_use);
    }
    BARRIER();  // B2: ss/s0a/xs updated for next step
  };

  // statically role-swapped 2x unroll (rule #20: no dynamic reg indexing)
  for (int tt = 0; tt < TT; tt += 2) {
    body(tt,     xvA, xvB);
    body(tt + 1, xvB, xvA);
  }

  // final output row (t = 255); s0a drained at last B2
  if (grp == 1) {
    f32x4 ov = *(const f32x4*)&s0a[fr1 * 68 + fd1];
    *(f32x4*)(out + ((size_t)(TT - 1) * NROW + row0 + fr1) * DD + fd1) = ov;
  }
}

extern "C" void kernel_launch(void* const* d_in, const int* in_sizes, int n_in,
                              void* d_out, int out_size, void* d_ws, size_t ws_size,
                              hipStream_t stream) {
  const float* x      = (const float*)d_in[0];
  const int*   mask   = (const int*)  d_in[1];
  const float* msg_W  = (const float*)d_in[2];
  const float* msg_b  = (const float*)d_in[3];
  const float* W_ih   = (const float*)d_in[4];
  const float* W_hh   = (const float*)d_in[5];
  const float* b_ih   = (const float*)d_in[6];
  const float* b_hh   = (const float*)d_in[7];
  const float* freq   = (const float*)d_in[8];
  const float* phase  = (const float*)d_in[9];
  float* out    = (float*)d_out;
  float* bias_t = (float*)d_ws;   // TT*DD floats = 64 KB

  (void)in_sizes; (void)n_in; (void)out_size; (void)ws_size;

  bias_kernel<<<TT, DD, 0, stream>>>(msg_W, msg_b, freq, phase, bias_t);
  scan8<<<GRID, BLK, 0, stream>>>(x, mask, msg_W, W_ih, W_hh,
                                  b_ih, b_hh, bias_t, out);
}